// Round 8
// baseline (333.653 us; speedup 1.0000x reference)
//
#include <hip/hip_runtime.h>

// INSTRUMENTATION ROUND — R5's proven 3-kernel structure with pass1/pass2
// bodies executed 3x so both phases exceed the ~73 µs fill cutoff and
// surface in the rocprof top-5 with full counters. Math is bit-identical
// to R5 (rep 0's result is the one stored; NT re-stores are idempotent).
// Load CSE across reps is defeated by laundering a zero offset through
// an empty asm; dead-code elimination of reps 1-2 is blocked by keeping
// their accumulators live via asm.
// What the counters will decide:
//   ipass1x3: FETCH tells whether x is HBM-cold or L3-resident at phase
//     start; (dur - 2*warm_rep) vs warm_rep separates BW/residency-limited
//     reads from a flat latency cap (~3 TB/s) that no structure can beat.
//   ipass2x3: dur/3 isolates the scan+normalize+NT-store phase; WRITE
//     ~370 MB, FETCH ~0 confirms L3 service of the x re-read.

#define ALPHA_F 0.99f
#define OMA_F   0.01f
#define EPS_F   1e-14f

constexpr int Bn = 16;
constexpr int Tn = 2000;
constexpr int Fn = 481;
constexpr int NC = 100;         // chunks along T
constexpr int L  = Tn / NC;     // 20 rows per chunk
constexpr int MT = 25;          // mid-kernel tile
#define ALPHA_L 0.817906938f    // 0.99^20

__global__ __launch_bounds__(256) void eun_pass1x3(
    const float* __restrict__ x, float* __restrict__ part) {
  const int f = blockIdx.x * blockDim.x + threadIdx.x;
  if (f >= Fn) return;
  const int b = blockIdx.y, c = blockIdx.z;

  const size_t stride = (size_t)Fn * 2;
  const float* xp0 = x + ((size_t)b * Tn + (size_t)c * L) * stride + (size_t)f * 2;

  float sKeep = 0.f;
  for (int rep = 0; rep < 3; ++rep) {
    int z = 0;
    asm volatile("" : "+v"(z));        // opaque 0: defeats load CSE across reps
    const float* xp = xp0 + z;
    float2 v[L];
#pragma unroll
    for (int j = 0; j < L; ++j)
      v[j] = *(const float2*)(xp + (size_t)j * stride);
    float s = 0.f;
#pragma unroll
    for (int j = 0; j < L; ++j) {
      float m = sqrtf(fmaxf(fmaf(v[j].x, v[j].x, v[j].y * v[j].y), EPS_F));
      s = fmaf(ALPHA_F, s, OMA_F * m);
    }
    if (rep == 0) sKeep = s;
    else asm volatile("" :: "v"(s));   // keep reps 1-2 live (no DCE)
  }
  part[((size_t)b * NC + c) * Fn + f] = sKeep;
}

// In-place: part[b,c,f] (chunk partial B_c) -> chunk-entry state S_c.
__global__ __launch_bounds__(256) void eun_mid(
    const float* __restrict__ init_state, float* __restrict__ part) {
  const int f = blockIdx.x * blockDim.x + threadIdx.x;
  if (f >= Fn) return;
  const int b = blockIdx.y;
  float* pp = part + (size_t)b * NC * Fn + f;
  float s = init_state[f];
  for (int c0 = 0; c0 < NC; c0 += MT) {
    float p[MT];
#pragma unroll
    for (int k = 0; k < MT; ++k) p[k] = pp[(size_t)(c0 + k) * Fn];
#pragma unroll
    for (int k = 0; k < MT; ++k) {
      pp[(size_t)(c0 + k) * Fn] = s;
      s = fmaf(s, ALPHA_L, p[k]);
    }
  }
}

__global__ __launch_bounds__(256) void eun_pass2x3(
    const float* __restrict__ x, const float* __restrict__ start,
    float* __restrict__ out) {
  const int f = blockIdx.x * blockDim.x + threadIdx.x;
  if (f >= Fn) return;
  const int b = blockIdx.y, c = blockIdx.z;

  const size_t stride = (size_t)Fn * 2;
  const size_t off = ((size_t)b * Tn + (size_t)c * L) * stride + (size_t)f * 2;
  const float* sp0 = start + ((size_t)b * NC + c) * Fn + f;

  for (int rep = 0; rep < 3; ++rep) {
    int z = 0;
    asm volatile("" : "+v"(z));        // opaque 0 per rep
    const float* xp = x + off + z;
    float*       op = (float*)(out + off + z);
    float s = sp0[z];                  // laundered reload of entry state

    float2 v[L];
#pragma unroll
    for (int j = 0; j < L; ++j)
      v[j] = *(const float2*)(xp + (size_t)j * stride);
#pragma unroll
    for (int j = 0; j < L; ++j) {
      float m = sqrtf(fmaxf(fmaf(v[j].x, v[j].x, v[j].y * v[j].y), EPS_F));
      s = fmaf(ALPHA_F, s, OMA_F * m);
      float inv = rsqrtf(s);
      union { float2 f2; unsigned long long u; } cvt;
      cvt.f2 = make_float2(v[j].x * inv, v[j].y * inv);
      // idempotent across reps: same values to same addresses
      __builtin_nontemporal_store(cvt.u,
          (unsigned long long*)(op + (size_t)j * stride));
    }
  }
}

extern "C" void kernel_launch(void* const* d_in, const int* in_sizes, int n_in,
                              void* d_out, int out_size, void* d_ws, size_t ws_size,
                              hipStream_t stream) {
  const float* x    = (const float*)d_in[0];
  const float* init = (const float*)d_in[1];
  float* out        = (float*)d_out;
  float* part       = (float*)d_ws;  // Bn*NC*Fn floats = 3.08 MB

  dim3 grid3((Fn + 255) / 256, Bn, NC);  // 2 x 16 x 100 = 3200 blocks
  eun_pass1x3<<<grid3, dim3(256), 0, stream>>>(x, part);
  eun_mid<<<dim3((Fn + 255) / 256, Bn), dim3(256), 0, stream>>>(init, part);
  eun_pass2x3<<<grid3, dim3(256), 0, stream>>>(x, part, out);
}

// Round 9
// 279.771 us; speedup vs baseline: 1.1926x; 1.1926x over previous
//
#include <hip/hip_runtime.h>

// ExponentialUnitNorm, 3-kernel split scan with pattern-matched streams
// (R8 instrumentation: cold STRIDED reads = 2.5 TB/s, LINEAR = 6.3+;
//  strided NT writes = 3.2 TB/s, linear = 6.7; L3-warm strided = ~free).
//   pass1lin: LINEAR float4 read of each chunk; per-chunk partial
//     B_c[f] = sum_t (1-a)*a^(L-1-t)*m[t,f] is order-free, accumulated
//     via LDS atomicAdd (ds_add_f32) with an alpha-power weight table.
//   mid: in-place partials -> chunk-entry states (proven R5 form).
//   pass2: strided float2 reads of x (L3-warm after pass1), register
//     scan + normalize, repack via double-buffered LDS, LINEAR float4
//     NT stores (proven correct in R7).
// NC=100 chunks (L=20), 1600 blocks per pass. absmax floor 0.03125
// (bf16-quantized comparison; weighted-sum reassoc ~1e-6 relative).

#define ALPHA_F 0.99f
#define OMA_F   0.01f
#define EPS_F   1e-14f

typedef float f32x4 __attribute__((ext_vector_type(4)));

constexpr int Bn = 16;
constexpr int Tn = 2000;
constexpr int Fn = 481;
constexpr int NC = 100;          // chunks along T
constexpr int L  = Tn / NC;      // 20 rows per chunk
constexpr int RF = 2 * Fn;       // floats per row = 962
constexpr int NF4 = L * RF / 4;  // 4810 float4 per chunk
constexpr int FULL = NF4 / 256;  // 18 full rounds
constexpr int REM  = NF4 - FULL * 256;  // 202
constexpr int ST = 4;            // pass2: rows per stage
constexpr int NST = L / ST;      // 5 stages
constexpr int SF4 = ST * RF / 4; // 962 float4 per stage
constexpr int TL3 = SF4 - 3 * 256;  // 194
constexpr int MT = 25;           // mid tile
#define ALPHA_L 0.817906938f     // 0.99^20

__global__ __launch_bounds__(256) void eun_pass1lin(
    const float* __restrict__ x, float* __restrict__ part) {
  __shared__ float B_lds[Fn];
  __shared__ float w_lds[L];
  const int tid = threadIdx.x;
  const int c = blockIdx.x, b = blockIdx.y;

  B_lds[tid] = 0.f;
  if (tid < Fn - 256) B_lds[tid + 256] = 0.f;
  if (tid < L) w_lds[tid] = OMA_F * powf(ALPHA_F, (float)(L - 1 - tid));
  __syncthreads();

  const f32x4* xb = (const f32x4*)(x + ((size_t)b * Tn + (size_t)c * L) * RF);

  // linear, fully-coalesced stream over the chunk; (t,f) via const-div
#pragma unroll 6
  for (int k = 0; k < FULL; ++k) {
    const int i = tid + 256 * k;
    f32x4 v = xb[i];
    const int g0 = 2 * i;
    const int t0 = g0 / Fn;            // magic-mul (Fn constant)
    const int f0 = g0 - t0 * Fn;
    float m0 = sqrtf(fmaxf(fmaf(v.x, v.x, v.y * v.y), EPS_F));
    atomicAdd(&B_lds[f0], w_lds[t0] * m0);
    int f1 = f0 + 1, t1 = t0;
    if (f1 == Fn) { f1 = 0; ++t1; }
    float m1 = sqrtf(fmaxf(fmaf(v.z, v.z, v.w * v.w), EPS_F));
    atomicAdd(&B_lds[f1], w_lds[t1] * m1);
  }
  if (tid < REM) {
    const int i = tid + 256 * FULL;
    f32x4 v = xb[i];
    const int g0 = 2 * i;
    const int t0 = g0 / Fn;
    const int f0 = g0 - t0 * Fn;
    float m0 = sqrtf(fmaxf(fmaf(v.x, v.x, v.y * v.y), EPS_F));
    atomicAdd(&B_lds[f0], w_lds[t0] * m0);
    int f1 = f0 + 1, t1 = t0;
    if (f1 == Fn) { f1 = 0; ++t1; }
    float m1 = sqrtf(fmaxf(fmaf(v.z, v.z, v.w * v.w), EPS_F));
    atomicAdd(&B_lds[f1], w_lds[t1] * m1);
  }
  __syncthreads();

  float* pp = part + ((size_t)b * NC + c) * Fn;
  pp[tid] = B_lds[tid];
  if (tid < Fn - 256) pp[tid + 256] = B_lds[tid + 256];
}

// In-place: part[b,c,f] (chunk partial B_c) -> chunk-entry state S_c.
__global__ __launch_bounds__(256) void eun_mid(
    const float* __restrict__ init_state, float* __restrict__ part) {
  const int f = blockIdx.x * blockDim.x + threadIdx.x;
  if (f >= Fn) return;
  const int b = blockIdx.y;
  float* pp = part + (size_t)b * NC * Fn + f;
  float s = init_state[f];
  for (int c0 = 0; c0 < NC; c0 += MT) {
    float p[MT];
#pragma unroll
    for (int k = 0; k < MT; ++k) p[k] = pp[(size_t)(c0 + k) * Fn];
#pragma unroll
    for (int k = 0; k < MT; ++k) {
      pp[(size_t)(c0 + k) * Fn] = s;          // S_c over B_c, in place
      s = fmaf(s, ALPHA_L, p[k]);             // S_{c+1} = aL*S_c + B_c
    }
  }
}

__global__ __launch_bounds__(256) void eun_pass2(
    const float* __restrict__ x, const float* __restrict__ start,
    float* __restrict__ out) {
  __shared__ f32x4 lds[2][SF4];
  const int tid = threadIdx.x;
  const int c = blockIdx.x, b = blockIdx.y;

  const size_t base_f = ((size_t)b * Tn + (size_t)c * L) * RF;
  const int f1 = tid, f2 = tid + 256;
  const bool a2 = (f2 < Fn);

  float s1 = start[((size_t)b * NC + c) * Fn + f1];
  float s2 = a2 ? start[((size_t)b * NC + c) * Fn + f2] : 0.f;

  const float* xp1 = x + base_f + (size_t)f1 * 2;
  const float* xp2 = x + base_f + (size_t)f2 * 2;

  float2 av[ST], qv[ST], an[ST], qn[ST];
  // prologue: stage-0 strided loads (L3-warm; x just streamed by pass1)
#pragma unroll
  for (int r = 0; r < ST; ++r) {
    av[r] = *(const float2*)(xp1 + (size_t)r * RF);
    if (a2) qv[r] = *(const float2*)(xp2 + (size_t)r * RF);
  }

  int cur = 0;
  for (int st = 0; st < NST; ++st) {
    // (a) issue next-stage loads (hide under compute)
    if (st + 1 < NST) {
      const float* p1 = xp1 + (size_t)(st + 1) * ST * RF;
      const float* p2 = xp2 + (size_t)(st + 1) * ST * RF;
#pragma unroll
      for (int r = 0; r < ST; ++r) {
        an[r] = *(const float2*)(p1 + (size_t)r * RF);
        if (a2) qn[r] = *(const float2*)(p2 + (size_t)r * RF);
      }
    }
    // (b) scan + normalize current stage into LDS
    float2* l2 = (float2*)lds[cur];
#pragma unroll
    for (int r = 0; r < ST; ++r) {
      float m = sqrtf(fmaxf(fmaf(av[r].x, av[r].x, av[r].y * av[r].y), EPS_F));
      s1 = fmaf(ALPHA_F, s1, OMA_F * m);
      float inv1 = rsqrtf(s1);
      l2[r * Fn + f1] = make_float2(av[r].x * inv1, av[r].y * inv1);
      if (a2) {
        float m2 = sqrtf(fmaxf(fmaf(qv[r].x, qv[r].x, qv[r].y * qv[r].y), EPS_F));
        s2 = fmaf(ALPHA_F, s2, OMA_F * m2);
        float inv2 = rsqrtf(s2);
        l2[r * Fn + f2] = make_float2(qv[r].x * inv2, qv[r].y * inv2);
      }
    }
    __syncthreads();  // one barrier per stage
    // (c) linear float4 NT store of this stage
    f32x4* ob = (f32x4*)(out + base_f) + (size_t)st * SF4;
    const f32x4* ls = (const f32x4*)lds[cur];
#pragma unroll
    for (int j = 0; j < 3; ++j) {
      f32x4 o = ls[tid + 256 * j];
      __builtin_nontemporal_store(o, ob + tid + 256 * j);
    }
    if (tid < TL3) {
      f32x4 o = ls[tid + 256 * 3];
      __builtin_nontemporal_store(o, ob + tid + 256 * 3);
    }
    // rotate prefetched regs
#pragma unroll
    for (int r = 0; r < ST; ++r) { av[r] = an[r]; qv[r] = qn[r]; }
    cur ^= 1;
  }
}

extern "C" void kernel_launch(void* const* d_in, const int* in_sizes, int n_in,
                              void* d_out, int out_size, void* d_ws, size_t ws_size,
                              hipStream_t stream) {
  const float* x    = (const float*)d_in[0];
  const float* init = (const float*)d_in[1];
  float* out        = (float*)d_out;
  float* part       = (float*)d_ws;  // Bn*NC*Fn floats = 3.08 MB

  dim3 grid(NC, Bn);  // 100 x 16 = 1600 blocks
  eun_pass1lin<<<grid, dim3(256), 0, stream>>>(x, part);
  eun_mid<<<dim3((Fn + 255) / 256, Bn), dim3(256), 0, stream>>>(init, part);
  eun_pass2<<<grid, dim3(256), 0, stream>>>(x, part, out);
}